// Round 5
// baseline (226.526 us; speedup 1.0000x reference)
//
#include <hip/hip_runtime.h>
#include <hip/hip_bf16.h>
#include <stdint.h>

#define BB 2
#define NN 2048
#define CC 1024
#define HH 16
#define DD 64
#define C3 3072

typedef __attribute__((ext_vector_type(8))) short bf16x8;
typedef __attribute__((ext_vector_type(4))) float f32x4;
typedef __attribute__((ext_vector_type(4))) unsigned short ushort4_t;

__device__ __forceinline__ unsigned short f2bf(float f) {
  union { float f; unsigned u; } v; v.f = f;
  unsigned r = v.u + 0x7FFFu + ((v.u >> 16) & 1u);
  return (unsigned short)(r >> 16);
}

#if __has_builtin(__builtin_amdgcn_exp2f)
#define EXP2(x) __builtin_amdgcn_exp2f(x)
#else
#define EXP2(x) exp2f(x)
#endif

// 0.125 (1/sqrt(D)) * log2(e): folded into Q so softmax uses raw v_exp_f32 (2^x)
#define QSCALE 0.18033688f

// async global->LDS, 16B per lane; LDS dest must be wave-uniform base + lane*16
#define GLDS(g, l) __builtin_amdgcn_global_load_lds( \
    (const __attribute__((address_space(1))) void*)(g), \
    (__attribute__((address_space(3))) void*)(l), 16, 0, 0)

// ----------------------------------------- merged fp32->bf16 converts (3 bufs)
__global__ __launch_bounds__(256) void k_cvt(
    const float* __restrict__ x, const float* __restrict__ wq,
    const float* __restrict__ wp,
    unsigned short* __restrict__ xb, unsigned short* __restrict__ wqb,
    unsigned short* __restrict__ wpb)
{
  int blk = blockIdx.x;
  const float* s; unsigned short* d; int i;
  if (blk < 4096)      { s = x;  d = xb;  i = blk * 256 + threadIdx.x; }
  else if (blk < 7168) { s = wq; d = wqb; i = (blk - 4096) * 256 + threadIdx.x; }
  else                 { s = wp; d = wpb; i = (blk - 7168) * 256 + threadIdx.x; }
  float4 v = ((const float4*)s)[i];
  ushort4_t o;
  o.x = f2bf(v.x); o.y = f2bf(v.y); o.z = f2bf(v.z); o.w = f2bf(v.w);
  ((ushort4_t*)d)[i] = o;
}

// -------------------------------- GEMM1 fused: qkv = x@Wqkv^T + b, RoPE, pack
__global__ __launch_bounds__(256) void k_gemm_qkv(
    const unsigned short* __restrict__ A, const unsigned short* __restrict__ Bt,
    const float* __restrict__ bias,
    const float* __restrict__ cosb, const float* __restrict__ sinb,
    unsigned short* __restrict__ Qg, unsigned short* __restrict__ Kg,
    unsigned short* __restrict__ Vnd)
{
  __shared__ __align__(16) unsigned short As[128 * 32];
  __shared__ __align__(16) unsigned short Bs[128 * 32];
  const int tid  = threadIdx.x;
  const int lane = tid & 63;
  const int wave = tid >> 6;
  const int bm = blockIdx.y * 128;
  const int bn = blockIdx.x * 128;
  const int wm = (wave >> 1) * 64;
  const int wn = (wave & 1) * 64;
  const int frow = lane & 15;
  const int fk   = (lane >> 4) * 8;
  const int K = 1024;

  f32x4 acc[4][4] = {};

  const int row0 = tid >> 2, cc0 = tid & 3;
  const int row1 = row0 + 64;

  for (int k0 = 0; k0 < K; k0 += 32) {
    GLDS(A  + (size_t)(bm + row0) * K + k0 + cc0 * 8, As + (size_t)tid * 8);
    GLDS(Bt + (size_t)(bn + row0) * K + k0 + cc0 * 8, Bs + (size_t)tid * 8);
    GLDS(A  + (size_t)(bm + row1) * K + k0 + cc0 * 8, As + (size_t)(tid + 256) * 8);
    GLDS(Bt + (size_t)(bn + row1) * K + k0 + cc0 * 8, Bs + (size_t)(tid + 256) * 8);
    __syncthreads();

    bf16x8 af[4], bfr[4];
#pragma unroll
    for (int t = 0; t < 4; ++t) {
      af[t]  = *(const bf16x8*)(As + (wm + t * 16 + frow) * 32 + fk);
      bfr[t] = *(const bf16x8*)(Bs + (wn + t * 16 + frow) * 32 + fk);
    }
#pragma unroll
    for (int mt = 0; mt < 4; ++mt)
#pragma unroll
      for (int nt = 0; nt < 4; ++nt)
        acc[mt][nt] = __builtin_amdgcn_mfma_f32_16x16x32_bf16(af[mt], bfr[nt], acc[mt][nt], 0, 0, 0);
    __syncthreads();
  }

  const int er0  = (lane >> 4) * 4;
  const int ecol = lane & 15;
  const int region = bn >> 10;                    // wave-uniform
  unsigned short* dstQK = (region == 0) ? Qg : Kg;

#pragma unroll
  for (int nt = 0; nt < 4; ++nt) {
    const int col = bn + wn + nt * 16 + ecol;     // global col in [0,3072)
    const float bv = bias[col];
    const int c64 = (wn + nt * 16 + ecol) & 63;   // d within head
    const int h   = (col >> 6) & 15;
    const int ii  = c64 >> 1;
#pragma unroll
    for (int mt = 0; mt < 4; ++mt)
#pragma unroll
      for (int r = 0; r < 4; ++r) {
        const int rowg = bm + wm + mt * 16 + er0 + r;
        const int b = rowg >> 11, n = rowg & (NN - 1);
        float v = acc[mt][nt][r] + bv;
        float vp = __shfl_xor(v, 1, 64);          // pair partner (col^1)
        const size_t o = ((size_t)(b * HH + h) * NN + n) * DD + c64;
        if (region == 2) {
          Vnd[o] = f2bf(v);
        } else {
          float cth = cosb[n * 32 + ii], sth = sinb[n * 32 + ii];
          float ov = (c64 & 1) ? (vp * sth + v * cth)
                               : (v * cth - vp * sth);
          if (region == 0) ov *= QSCALE;
          dstQK[o] = f2bf(ov);
        }
      }
  }
}

// ------------------------------------- V transpose: Vnd[bh][n][d] -> Vt[bh][d][n]
__global__ __launch_bounds__(256) void k_vt(
    const unsigned short* __restrict__ Vnd, unsigned short* __restrict__ Vt)
{
  __shared__ unsigned short t[64][66];
  const int tid = threadIdx.x;
  const int bh = blockIdx.x >> 5;
  const int n0 = (blockIdx.x & 31) * 64;

  const unsigned short* src = Vnd + ((size_t)bh * NN + n0) * DD;
  const int nl = tid >> 2, d0 = (tid & 3) * 16;
#pragma unroll
  for (int j = 0; j < 4; ++j) {
    ushort4_t v = *(const ushort4_t*)(src + (size_t)nl * DD + d0 + j * 4);
    t[nl][d0 + j * 4 + 0] = v.x;
    t[nl][d0 + j * 4 + 1] = v.y;
    t[nl][d0 + j * 4 + 2] = v.z;
    t[nl][d0 + j * 4 + 3] = v.w;
  }
  __syncthreads();
  const int d = tid >> 2, m0 = (tid & 3) * 16;
  unsigned short* dst = Vt + ((size_t)bh * DD + d) * NN + n0 + m0;
#pragma unroll
  for (int j = 0; j < 4; ++j) {
    ushort4_t o;
    o.x = t[m0 + j * 4 + 0][d];
    o.y = t[m0 + j * 4 + 1][d];
    o.z = t[m0 + j * 4 + 2][d];
    o.w = t[m0 + j * 4 + 3][d];
    *(ushort4_t*)(dst + j * 4) = o;
  }
}

// ----------------------------------------------------- flash attention v5
// 32 q-rows per wave (2 m-frags): each K/V fragment ds_read now feeds 2x the
// MFMAs (DS pipe was ~90% saturated in v4). grid 512 (128 q/block), 48KB LDS,
// 2 blocks/CU = 8 waves/CU. Double-buffered Ks/Vs, one barrier/iter; Ps
// wave-private; row-sums via ones-MFMA; p = 2^s; truncating bf16 P store.
__global__ __launch_bounds__(256) void k_attn(
    const unsigned short* __restrict__ Qg, const unsigned short* __restrict__ Kg,
    const unsigned short* __restrict__ Vtg, unsigned short* __restrict__ Og)
{
  __shared__ __align__(16) unsigned short Ks[2][64 * 64];
  __shared__ __align__(16) unsigned short Vs[2][64 * 64];
  __shared__ __align__(16) unsigned short Ps[4][32 * 64];

  const int tid  = threadIdx.x;
  const int lane = tid & 63;
  const int wave = tid >> 6;
  const int bh = blockIdx.x >> 4;     // 16 q-tiles of 128 per bh
  const int qt = blockIdx.x & 15;
  const int q0 = qt * 128 + wave * 32;
  const int frow   = lane & 15;
  const int fchunk = lane >> 4;
  const int er0  = (lane >> 4) * 4;
  const int ecol = lane & 15;

  const unsigned short* Qb = Qg  + (size_t)bh * NN * DD;
  const unsigned short* Kb = Kg  + (size_t)bh * NN * DD;
  const unsigned short* Vb = Vtg + (size_t)bh * DD * NN;

  bf16x8 qf[2][2];
#pragma unroll
  for (int m = 0; m < 2; ++m)
#pragma unroll
    for (int kt = 0; kt < 2; ++kt)
      qf[m][kt] = *(const bf16x8*)(Qb + (size_t)(q0 + m * 16 + frow) * DD + kt * 32 + fchunk * 8);

  bf16x8 ones;
#pragma unroll
  for (int i = 0; i < 8; ++i) ones[i] = (short)0x3F80;

  f32x4 oacc[2][4] = {};
  f32x4 lacc[2] = {};

  const int row0 = tid >> 3, cc0 = tid & 7;
  const int sw0 = (cc0 ^ (row0 & 7)) * 8;

  GLDS(Kb + (size_t)row0 * DD + sw0,        Ks[0] + (size_t)tid * 8);
  GLDS(Vb + (size_t)row0 * NN + sw0,        Vs[0] + (size_t)tid * 8);
  GLDS(Kb + (size_t)(row0 + 32) * DD + sw0, Ks[0] + (size_t)(tid + 256) * 8);
  GLDS(Vb + (size_t)(row0 + 32) * NN + sw0, Vs[0] + (size_t)(tid + 256) * 8);

  for (int t = 0; t < NN / 64; ++t) {
    const int p = t & 1;
    __syncthreads();

    if (t + 1 < NN / 64) {
      const int j = (t + 1) * 64;
      GLDS(Kb + (size_t)(j + row0) * DD + sw0,      Ks[1 - p] + (size_t)tid * 8);
      GLDS(Vb + (size_t)row0 * NN + j + sw0,        Vs[1 - p] + (size_t)tid * 8);
      GLDS(Kb + (size_t)(j + row0 + 32) * DD + sw0, Ks[1 - p] + (size_t)(tid + 256) * 8);
      GLDS(Vb + (size_t)(row0 + 32) * NN + j + sw0, Vs[1 - p] + (size_t)(tid + 256) * 8);
    }

    // S = Q K^T : 2 m-frags x 4 kv-frags; K frags read once, used twice
    f32x4 sacc[2][4] = {};
#pragma unroll
    for (int nt = 0; nt < 4; ++nt) {
      int kr = nt * 16 + frow;
      bf16x8 kf0 = *(const bf16x8*)(Ks[p] + kr * 64 + ((fchunk       ^ (kr & 7)) << 3));
      bf16x8 kf1 = *(const bf16x8*)(Ks[p] + kr * 64 + (((fchunk + 4) ^ (kr & 7)) << 3));
#pragma unroll
      for (int m = 0; m < 2; ++m) {
        sacc[m][nt] = __builtin_amdgcn_mfma_f32_16x16x32_bf16(qf[m][0], kf0, sacc[m][nt], 0, 0, 0);
        sacc[m][nt] = __builtin_amdgcn_mfma_f32_16x16x32_bf16(qf[m][1], kf1, sacc[m][nt], 0, 0, 0);
      }
    }

    // p = 2^s (scale folded into Q); truncating bf16 store into wave-private Ps
#pragma unroll
    for (int m = 0; m < 2; ++m)
#pragma unroll
      for (int r = 0; r < 4; ++r) {
        int prow = m * 16 + er0 + r;
#pragma unroll
        for (int nt = 0; nt < 4; ++nt) {
          float pv = EXP2(sacc[m][nt][r]);
          union { float f; unsigned u; } cv; cv.f = pv;
          int col = nt * 16 + ecol;
          Ps[wave][prow * 64 + (((col >> 3) ^ (prow & 7)) << 3) + (col & 7)] =
              (unsigned short)(cv.u >> 16);
        }
      }

    // O += P V ; l += P @ 1 ; V frags read once, used for both m-frags
    bf16x8 pf0[2], pf1[2];
#pragma unroll
    for (int m = 0; m < 2; ++m) {
      int pr = m * 16 + frow;
      pf0[m] = *(const bf16x8*)(&Ps[wave][pr * 64 + ((fchunk       ^ (pr & 7)) << 3)]);
      pf1[m] = *(const bf16x8*)(&Ps[wave][pr * 64 + (((fchunk + 4) ^ (pr & 7)) << 3)]);
      lacc[m] = __builtin_amdgcn_mfma_f32_16x16x32_bf16(pf0[m], ones, lacc[m], 0, 0, 0);
      lacc[m] = __builtin_amdgcn_mfma_f32_16x16x32_bf16(pf1[m], ones, lacc[m], 0, 0, 0);
    }
#pragma unroll
    for (int dt = 0; dt < 4; ++dt) {
      int vr = dt * 16 + frow;
      bf16x8 vf0 = *(const bf16x8*)(Vs[p] + vr * 64 + ((fchunk       ^ (vr & 7)) << 3));
      bf16x8 vf1 = *(const bf16x8*)(Vs[p] + vr * 64 + (((fchunk + 4) ^ (vr & 7)) << 3));
#pragma unroll
      for (int m = 0; m < 2; ++m) {
        oacc[m][dt] = __builtin_amdgcn_mfma_f32_16x16x32_bf16(pf0[m], vf0, oacc[m][dt], 0, 0, 0);
        oacc[m][dt] = __builtin_amdgcn_mfma_f32_16x16x32_bf16(pf1[m], vf1, oacc[m][dt], 0, 0, 0);
      }
    }
  }

  const int b = bh >> 4;
  const int h = bh & 15;
#pragma unroll
  for (int m = 0; m < 2; ++m)
#pragma unroll
    for (int dt = 0; dt < 4; ++dt)
#pragma unroll
      for (int r = 0; r < 4; ++r) {
        int qrow = q0 + m * 16 + er0 + r;
        int d = dt * 16 + ecol;
        float v = oacc[m][dt][r] / lacc[m][r];
        Og[(size_t)(b * NN + qrow) * CC + h * DD + d] = f2bf(v);
      }
}

// ------------------------------- GEMM2: out = aob @ Wproj^T + b (fp32 out)
__global__ __launch_bounds__(256) void k_gemm_proj(
    const unsigned short* __restrict__ A, const unsigned short* __restrict__ Bt,
    const float* __restrict__ bias, float* __restrict__ Co)
{
  __shared__ __align__(16) unsigned short As[64 * 32];
  __shared__ __align__(16) unsigned short Bs[128 * 32];
  const int tid  = threadIdx.x;
  const int lane = tid & 63;
  const int wave = tid >> 6;
  const int bm = blockIdx.y * 64;
  const int bn = blockIdx.x * 128;
  const int wm = (wave >> 1) * 32;
  const int wn = (wave & 1) * 64;
  const int frow = lane & 15;
  const int fk   = (lane >> 4) * 8;
  const int K = 1024;

  f32x4 acc[2][4] = {};

  const int row0 = tid >> 2, cc0 = tid & 3;

  for (int k0 = 0; k0 < K; k0 += 32) {
    GLDS(A  + (size_t)(bm + row0) * K + k0 + cc0 * 8, As + (size_t)tid * 8);
    GLDS(Bt + (size_t)(bn + row0) * K + k0 + cc0 * 8, Bs + (size_t)tid * 8);
    GLDS(Bt + (size_t)(bn + row0 + 64) * K + k0 + cc0 * 8, Bs + (size_t)(tid + 256) * 8);
    __syncthreads();

    bf16x8 af[2], bfr[4];
#pragma unroll
    for (int t = 0; t < 2; ++t)
      af[t] = *(const bf16x8*)(As + (wm + t * 16 + frow) * 32 + fk);
#pragma unroll
    for (int t = 0; t < 4; ++t)
      bfr[t] = *(const bf16x8*)(Bs + (wn + t * 16 + frow) * 32 + fk);
#pragma unroll
    for (int mt = 0; mt < 2; ++mt)
#pragma unroll
      for (int nt = 0; nt < 4; ++nt)
        acc[mt][nt] = __builtin_amdgcn_mfma_f32_16x16x32_bf16(af[mt], bfr[nt], acc[mt][nt], 0, 0, 0);
    __syncthreads();
  }

  const int er0  = (lane >> 4) * 4;
  const int ecol = lane & 15;
#pragma unroll
  for (int nt = 0; nt < 4; ++nt) {
    int col = bn + wn + nt * 16 + ecol;
    float bv = bias[col];
#pragma unroll
    for (int mt = 0; mt < 2; ++mt)
#pragma unroll
      for (int r = 0; r < 4; ++r) {
        int rowg = bm + wm + mt * 16 + er0 + r;
        Co[(size_t)rowg * CC + col] = acc[mt][nt][r] + bv;
      }
  }
}

// ---------------------------------------------------------------- launcher
extern "C" void kernel_launch(void* const* d_in, const int* in_sizes, int n_in,
                              void* d_out, int out_size, void* d_ws, size_t ws_size,
                              hipStream_t stream)
{
  const float* x      = (const float*)d_in[0];
  const float* w_qkv  = (const float*)d_in[1];
  const float* b_qkv  = (const float*)d_in[2];
  const float* w_proj = (const float*)d_in[3];
  const float* b_proj = (const float*)d_in[4];
  const float* fcos   = (const float*)d_in[5];
  const float* fsin   = (const float*)d_in[6];
  float* out = (float*)d_out;

  char* ws = (char*)d_ws;
  unsigned short* xb     = (unsigned short*)(ws);              //  8 MB
  unsigned short* wqkvb  = (unsigned short*)(ws + 8388608);    //  6 MB
  unsigned short* wprojb = (unsigned short*)(ws + 14680064);   //  2 MB
  unsigned short* Qb     = (unsigned short*)(ws + 16777216);   //  8 MB
  unsigned short* Kb     = (unsigned short*)(ws + 25165824);   //  8 MB
  unsigned short* Vnd    = (unsigned short*)(ws + 33554432);   //  8 MB
  unsigned short* Vtb    = (unsigned short*)(ws + 41943040);   //  8 MB
  unsigned short* aob    = (unsigned short*)(ws + 50331648);   //  8 MB

  k_cvt<<<8192, 256, 0, stream>>>(x, w_qkv, w_proj, xb, wqkvb, wprojb);

  k_gemm_qkv<<<dim3(24, 32), 256, 0, stream>>>(xb, wqkvb, b_qkv, fcos, fsin,
                                               Qb, Kb, Vnd);
  k_vt<<<1024, 256, 0, stream>>>(Vnd, Vtb);

  k_attn<<<512, 256, 0, stream>>>(Qb, Kb, Vtb, aob);

  k_gemm_proj<<<dim3(8, 64), 256, 0, stream>>>(aob, wprojb, b_proj, out);
}